// Round 4
// baseline (159.547 us; speedup 1.0000x reference)
//
#include <hip/hip_runtime.h>

#define HF 400
#define WF 400
#define NB 8
#define ND 96
#define NH 192
#define NW 192
#define TH 8   // h-values per thread

// Pass 1: transpose fluence [B, HF, WF] -> ws [HF, WF, B] so all 8 batch
// values for one pixel are 32 contiguous bytes (a corner-pair = 64 B).
__global__ __launch_bounds__(256) void fluence_interleave_kernel(
    const float* __restrict__ fluence,  // [B, HF, WF]
    float* __restrict__ wsf)            // [HF*WF, B]
{
    const int p = blockIdx.x * 256 + threadIdx.x;   // pixel index 0..159999
    if (p >= HF * WF) return;
    float v[NB];
#pragma unroll
    for (int b = 0; b < NB; ++b) v[b] = fluence[b * (HF * WF) + p];  // coalesced per b
    float4* dst = (float4*)(wsf + (size_t)p * NB);
    dst[0] = make_float4(v[0], v[1], v[2], v[3]);
    dst[1] = make_float4(v[4], v[5], v[6], v[7]);
}

// Pass 2: thread owns (d,w), loops TH h-values. For each row, ONE 64-B block
// [cy, xb..xb+1, b=0..7] fetched as 4 dwordx4 loads with imm offsets.
__global__ __launch_bounds__(NW) void fluence_vol_kernel(
    const float* __restrict__ wsf,       // [HF, WF, B] interleaved
    const float* __restrict__ grids,     // [D, W, H, 2]
    const float* __restrict__ pc,        // [D]
    float* __restrict__ out)             // [B, D, H, W]
{
    const int w  = threadIdx.x;
    const int h0 = blockIdx.x * TH;
    const int d  = blockIdx.y;

    // ---- per-thread x path (once per 8*TH outputs) ----
    const float x = grids[(d * NW + w) * NH * 2];
    const float ix = ((x + 1.0f) * WF - 1.0f) * 0.5f;
    const float ix0f = floorf(ix);
    const int ix0 = (int)ix0f;
    const int ix1 = ix0 + 1;
    const float wx1 = ix - ix0f;
    const float wx0 = 1.0f - wx1;
    const int cx0 = min(max(ix0, 0), WF - 1);
    const int cx1 = min(max(ix1, 0), WF - 1);
    const int xb  = min(max(ix0, 0), WF - 2);   // pair window [xb, xb+1]
    const float wxv0 = ((ix0 >= 0) && (ix0 < WF)) ? wx0 : 0.0f;
    const float wxv1 = ((ix1 >= 0) && (ix1 < WF)) ? wx1 : 0.0f;
    const float ax = ((cx0 == xb)     ? wxv0 : 0.0f) + ((cx1 == xb)     ? wxv1 : 0.0f);
    const float bx = ((cx0 == xb + 1) ? wxv0 : 0.0f) + ((cx1 == xb + 1) ? wxv1 : 0.0f);

    const float corr = pc[d];
    const float* __restrict__ gy = grids + (d * NW * NH) * 2 + 1;

#pragma unroll
    for (int hh = 0; hh < TH; ++hh) {
        const int h = h0 + hh;
        // ---- block-uniform y path ----
        const float y = gy[h * 2];
        const float iy = ((y + 1.0f) * HF - 1.0f) * 0.5f;
        const float iy0f = floorf(iy);
        const int iy0 = (int)iy0f;
        const int iy1 = iy0 + 1;
        const float wy1 = iy - iy0f;
        const float wy0 = 1.0f - wy1;
        const int cy0 = min(max(iy0, 0), HF - 1);
        const int cy1 = min(max(iy1, 0), HF - 1);
        const float wyc0 = (((iy0 >= 0) && (iy0 < HF)) ? wy0 : 0.0f) * corr;
        const float wyc1 = (((iy1 >= 0) && (iy1 < HF)) ? wy1 : 0.0f) * corr;

        // 64-B corner-pair blocks for all 8 batches
        const float4* r0 = (const float4*)(wsf + (size_t)(cy0 * WF + xb) * NB);
        const float4* r1 = (const float4*)(wsf + (size_t)(cy1 * WF + xb) * NB);
        const float4 a0 = r0[0], a1 = r0[1];   // row cy0, x=xb,   b0..7
        const float4 a2 = r0[2], a3 = r0[3];   // row cy0, x=xb+1, b0..7
        const float4 c0 = r1[0], c1 = r1[1];   // row cy1, x=xb,   b0..7
        const float4 c2 = r1[2], c3 = r1[3];   // row cy1, x=xb+1, b0..7

        const float f0[NB] = {a0.x, a0.y, a0.z, a0.w, a1.x, a1.y, a1.z, a1.w};
        const float f1[NB] = {a2.x, a2.y, a2.z, a2.w, a3.x, a3.y, a3.z, a3.w};
        const float g0[NB] = {c0.x, c0.y, c0.z, c0.w, c1.x, c1.y, c1.z, c1.w};
        const float g1[NB] = {c2.x, c2.y, c2.z, c2.w, c3.x, c3.y, c3.z, c3.w};

        float* op = out + (size_t)d * NH * NW + (size_t)h * NW + w;
#pragma unroll
        for (int b = 0; b < NB; ++b) {
            const float v0 = fmaf(f1[b], bx, f0[b] * ax);
            const float v1 = fmaf(g1[b], bx, g0[b] * ax);
            const float v  = fmaf(v1, wyc1, v0 * wyc0);
            __builtin_nontemporal_store(v, op + (size_t)b * (ND * NH * NW));
        }
    }
}

extern "C" void kernel_launch(void* const* d_in, const int* in_sizes, int n_in,
                              void* d_out, int out_size, void* d_ws, size_t ws_size,
                              hipStream_t stream) {
    const float* fluence = (const float*)d_in[0];  // [8, 400, 400]
    const float* grids   = (const float*)d_in[1];  // [96, 192, 192, 2]
    const float* pc      = (const float*)d_in[2];  // [96]
    float* out = (float*)d_out;                    // [8, 96, 192, 192]
    float* wsf = (float*)d_ws;                     // [400*400*8] = 5.12 MB

    fluence_interleave_kernel<<<(HF * WF + 255) / 256, 256, 0, stream>>>(fluence, wsf);

    dim3 grid(NH / TH, ND);   // (h-tile, d)
    dim3 block(NW);           // w
    fluence_vol_kernel<<<grid, block, 0, stream>>>(wsf, grids, pc, out);
}